// Round 3
// baseline (158.367 us; speedup 1.0000x reference)
//
#include <hip/hip_runtime.h>

// Decoder: N=4096 LSTM sequences (K=16 x B=256), H=64, T=50, GMM head (GC=16, PD=2).
// Round 3: 512 blocks x 256 threads (4 waves) x 8 samples; ONE barrier per step.
//  - Wave w owns gate tiles i/f/g/o for units [16w,16w+16) -> cell update fully
//    in registers (no gate LDS exchange, c-state lane-resident).
//  - h double-buffered in LDS as bf16 hi/lo A-frags; proj reuses gates' A-frags.
//  - PL double-buffered; GMM(t-1) overlaps gates/cell/proj of step t.
//  - 2 blocks/CU for cross-block latency hiding.

#define T_ 50
#define SPB 8
#define ZXS 324
#define HFS 72
#define PLS 100

typedef __attribute__((ext_vector_type(8))) short short8;
typedef __attribute__((ext_vector_type(4))) float f32x4;

#define MFMA(a, b, c) __builtin_amdgcn_mfma_f32_16x16x32_bf16(a, b, c, 0, 0, 0)

__device__ __forceinline__ float sigf(float x)  { return 1.0f / (1.0f + __expf(-x)); }
__device__ __forceinline__ float tanh_(float x) { return 1.0f - 2.0f / (__expf(2.0f * x) + 1.0f); }

__device__ __forceinline__ void splitf(float f, unsigned short& hi, unsigned short& lo) {
    unsigned b = __float_as_uint(f);
    hi = (unsigned short)(b >> 16);
    float fh = __uint_as_float(b & 0xffff0000u);
    lo = (unsigned short)(__float_as_uint(f - fh) >> 16);
}

__device__ __forceinline__ void pack8(const float* p, short8& hi, short8& lo) {
    #pragma unroll
    for (int e = 0; e < 8; ++e) {
        unsigned short h, l;
        splitf(p[e], h, l);
        hi[e] = (short)h; lo[e] = (short)l;
    }
}

__launch_bounds__(256, 2)
__global__ void decoder_kernel(
    const float* __restrict__ x,       const float* __restrict__ z,
    const float* __restrict__ inp_seqs,const float* __restrict__ pred_seqs,
    const float* __restrict__ Wh0,     const float* __restrict__ bh0,
    const float* __restrict__ Wc0,     const float* __restrict__ bc0,
    const float* __restrict__ Wih,     const float* __restrict__ Whh,
    const float* __restrict__ bih,     const float* __restrict__ bhh,
    const float* __restrict__ Wpi,     const float* __restrict__ bpi,
    const float* __restrict__ Wmu,     const float* __restrict__ bmu,
    const float* __restrict__ Wls,     const float* __restrict__ bls,
    const float* __restrict__ Wcorr,   const float* __restrict__ bcorr,
    float* __restrict__ out)
{
    // floats: [0,5184) ZXL 16x324 (prologue) / PL0 [0,800) PL1 [800,1600) (main)
    //         [5184,7488) HF: 4 ushort arrays of 16x72 (hi0,lo0,hi1,lo1)
    //         [7488,8288) FUT 50x16   [8288,8320) PRS
    __shared__ __align__(16) float smem[8320];
    float* ZXL = smem;
    float* PL0 = smem;
    float* PL1 = smem + 800;
    unsigned short* HF0h = (unsigned short*)(smem + 5184);
    unsigned short* HF0l = HF0h + 1152;
    unsigned short* HF1h = HF0h + 2304;
    unsigned short* HF1l = HF0h + 3456;
    float* FUT = smem + 7488;
    float* PRS = smem + 8288;

    const int j = threadIdx.x;
    const int w = j >> 6;     // wave 0..3
    const int l = j & 63;
    const int g = l >> 4;     // k-group / D-row-group
    const int c = l & 15;     // A-row (sample) / B-col (unit)
    const int blk = blockIdx.x;

    // ---- fill ZXL (rows>=8 and cols>=320 zeroed), zero HF, FUT, PRS
    for (int e = j; e < 16*ZXS; e += 256) {
        int s = e / ZXS, k = e - s*ZXS;
        float v = 0.0f;
        if (s < SPB && k < 320) {
            int n = blk*SPB + s, kk = n >> 8, b = n & 255;
            v = (k < 64) ? z[(kk*256 + b)*64 + k] : x[b*256 + (k - 64)];
        }
        ZXL[s*ZXS + k] = v;
    }
    for (int e = j; e < 2304; e += 256) smem[5184 + e] = 0.0f;   // zero all HF
    for (int e = j; e < T_*SPB; e += 256) {
        int t = e >> 3, s = e & 7;
        int b = (blk*SPB + s) & 255;
        float2 v = *reinterpret_cast<const float2*>(pred_seqs + b*1200 + t*24 + 20);
        FUT[t*16 + s*2] = v.x; FUT[t*16 + s*2 + 1] = v.y;
    }
    if (j >= 16 && j < 32) PRS[j] = 0.0f;
    if (j < SPB) {
        int b = (blk*SPB + j) & 255;
        float2 v = *reinterpret_cast<const float2*>(inp_seqs + b*192 + 188);
        PRS[j*2] = v.x; PRS[j*2 + 1] = v.y;
    }
    __syncthreads();

    // ---- prologue MFMA: gates_const (i,f,g,o for units 16w+c), h0, c0
    const int U  = 16*w + c;          // this lane's unit column
    const int R0 = U, R1 = 64 + U, R2 = 128 + U, R3 = 192 + U;

    f32x4 gci, gcf, gcg, gco, h0a, c0a;
    {
        float bi_ = bih[R0] + bhh[R0], bf_ = bih[R1] + bhh[R1];
        float bg_ = bih[R2] + bhh[R2], bo_ = bih[R3] + bhh[R3];
        float bh_ = bh0[U], bc_ = bc0[U];
        gci = (f32x4){bi_,bi_,bi_,bi_}; gcf = (f32x4){bf_,bf_,bf_,bf_};
        gcg = (f32x4){bg_,bg_,bg_,bg_}; gco = (f32x4){bo_,bo_,bo_,bo_};
        h0a = (f32x4){bh_,bh_,bh_,bh_}; c0a = (f32x4){bc_,bc_,bc_,bc_};
    }
    for (int ks = 0; ks < 10; ++ks) {
        int k0 = ks*32 + g*8;
        short8 ah, al, bh0_, bl0_, bh1_, bl1_, bh2_, bl2_, bh3_, bl3_, bhh_, bhl_, bch_, bcl_;
        pack8(&ZXL[c*ZXS + k0], ah, al);
        pack8(Wih + R0*322 + k0, bh0_, bl0_);
        pack8(Wih + R1*322 + k0, bh1_, bl1_);
        pack8(Wih + R2*322 + k0, bh2_, bl2_);
        pack8(Wih + R3*322 + k0, bh3_, bl3_);
        pack8(Wh0 + U*320 + k0, bhh_, bhl_);
        pack8(Wc0 + U*320 + k0, bch_, bcl_);
        gci = MFMA(ah, bh0_, gci); gci = MFMA(ah, bl0_, gci); gci = MFMA(al, bh0_, gci);
        gcf = MFMA(ah, bh1_, gcf); gcf = MFMA(ah, bl1_, gcf); gcf = MFMA(al, bh1_, gcf);
        gcg = MFMA(ah, bh2_, gcg); gcg = MFMA(ah, bl2_, gcg); gcg = MFMA(al, bh2_, gcg);
        gco = MFMA(ah, bh3_, gco); gco = MFMA(ah, bl3_, gco); gco = MFMA(al, bh3_, gco);
        h0a = MFMA(ah, bhh_, h0a); h0a = MFMA(ah, bhl_, h0a); h0a = MFMA(al, bhh_, h0a);
        c0a = MFMA(ah, bch_, c0a); c0a = MFMA(ah, bcl_, c0a); c0a = MFMA(al, bch_, c0a);
    }
    // H_0 -> HF0 (rows 0..7); c0 -> regs
    float cst[4];
    #pragma unroll
    for (int r = 0; r < 4; ++r) {
        cst[r] = c0a[r];
        unsigned short hh, ll; splitf(h0a[r], hh, ll);
        if (g < 2) {
            HF0h[(4*g + r)*HFS + U] = hh;
            HF0l[(4*g + r)*HFS + U] = ll;
        }
    }

    // d-weights (cols 320,321 of Wih)
    const float wdi0 = Wih[R0*322+320], wdi1 = Wih[R0*322+321];
    const float wdf0 = Wih[R1*322+320], wdf1 = Wih[R1*322+321];
    const float wdg0 = Wih[R2*322+320], wdg1 = Wih[R2*322+321];
    const float wdo0 = Wih[R3*322+320], wdo1 = Wih[R3*322+321];

    // Whh B-frags: 4 tiles x 2 kslices x hi/lo
    short8 WIh0,WIl0,WIh1,WIl1, WFh0,WFl0,WFh1,WFl1, WGh0,WGl0,WGh1,WGl1, WOh0,WOl0,WOh1,WOl1;
    pack8(Whh + R0*64 +      g*8, WIh0, WIl0); pack8(Whh + R0*64 + 32 + g*8, WIh1, WIl1);
    pack8(Whh + R1*64 +      g*8, WFh0, WFl0); pack8(Whh + R1*64 + 32 + g*8, WFh1, WFl1);
    pack8(Whh + R2*64 +      g*8, WGh0, WGl0); pack8(Whh + R2*64 + 32 + g*8, WGh1, WGl1);
    pack8(Whh + R3*64 +      g*8, WOh0, WOl0); pack8(Whh + R3*64 + 32 + g*8, WOh1, WOl1);

    // proj tiles: wave w -> tile w; waves 0,1 also tiles 4,5
    auto projrow = [&](int r3, const float*& p, float& b) {
        if      (r3 < 16) { p = Wpi   + r3*64;      b = bpi[r3]; }
        else if (r3 < 48) { p = Wmu   + (r3-16)*64; b = bmu[r3-16]; }
        else if (r3 < 80) { p = Wls   + (r3-48)*64; b = bls[r3-48]; }
        else              { p = Wcorr + (r3-80)*64; b = bcorr[r3-80]; }
    };
    const int pt0 = w, pt1 = w + 4;
    short8 q0h0,q0l0,q0h1,q0l1, q1h0={0},q1l0={0},q1h1={0},q1l1={0};
    float bias3_0, bias3_1 = 0.0f;
    {
        const float* p; projrow(pt0*16 + c, p, bias3_0);
        pack8(p +      g*8, q0h0, q0l0);
        pack8(p + 32 + g*8, q0h1, q0l1);
    }
    if (w < 2) {
        const float* p; projrow(pt1*16 + c, p, bias3_1);
        pack8(p +      g*8, q1h0, q1l0);
        pack8(p + 32 + g*8, q1h1, q1l1);
    }

    const int s3 = (j >> 4) & 7, g3 = j & 15;
    float sum = 0.0f;

    auto do_proj = [&](short8 ah0, short8 al0, short8 ah1, short8 al1, float* PLw) {
        f32x4 p0 = (f32x4){bias3_0, bias3_0, bias3_0, bias3_0};
        p0 = MFMA(ah0,q0h0,p0); p0 = MFMA(ah0,q0l0,p0); p0 = MFMA(al0,q0h0,p0);
        p0 = MFMA(ah1,q0h1,p0); p0 = MFMA(ah1,q0l1,p0); p0 = MFMA(al1,q0h1,p0);
        if (g < 2) {
            #pragma unroll
            for (int r = 0; r < 4; ++r) PLw[(4*g + r)*PLS + pt0*16 + c] = p0[r];
        }
        if (w < 2) {
            f32x4 p1 = (f32x4){bias3_1, bias3_1, bias3_1, bias3_1};
            p1 = MFMA(ah0,q1h0,p1); p1 = MFMA(ah0,q1l0,p1); p1 = MFMA(al0,q1h0,p1);
            p1 = MFMA(ah1,q1h1,p1); p1 = MFMA(ah1,q1l1,p1); p1 = MFMA(al1,q1h1,p1);
            if (g < 2) {
                #pragma unroll
                for (int r = 0; r < 4; ++r) PLw[(4*g + r)*PLS + pt1*16 + c] = p1[r];
            }
        }
    };
    auto do_gmm = [&](const float* pl, const float* fut2) {
        const float* pls = pl + s3*PLS;
        float a_pi = pls[g3];
        float a_m0 = pls[16 + 2*g3], a_m1 = pls[17 + 2*g3];
        float l0   = pls[48 + 2*g3], l1   = pls[49 + 2*g3];
        float a_co = pls[80 + g3];
        float v0 = fut2[s3*2], v1 = fut2[s3*2 + 1];
        l0 = fminf(fmaxf(l0, -10.0f), 10.0f);
        l1 = fminf(fmaxf(l1, -10.0f), 10.0f);
        float z0 = (v0 - a_m0) * __expf(-l0);
        float z1 = (v1 - a_m1) * __expf(-l1);
        float ct = tanh_(a_co);
        float omr = 1.0f - ct*ct;
        float quad = z0*z0 + z1*z1 - 2.0f*ct*z0*z1;
        float comp = -1.8378770664093453f - (l0 + l1) - 0.5f*__logf(omr) - 0.5f*quad/omr;
        float a = a_pi + comp;
        float m1v = a, m2v = a_pi;
        #pragma unroll
        for (int off = 1; off < 16; off <<= 1) {
            m1v = fmaxf(m1v, __shfl_xor(m1v, off));
            m2v = fmaxf(m2v, __shfl_xor(m2v, off));
        }
        float e1 = __expf(a - m1v), e2 = __expf(a_pi - m2v);
        #pragma unroll
        for (int off = 1; off < 16; off <<= 1) {
            e1 += __shfl_xor(e1, off);
            e2 += __shfl_xor(e2, off);
        }
        float logp = (m1v + __logf(e1)) - (m2v + __logf(e2));
        sum += fminf(logp, 50.0f);
    };

    __syncthreads();   // H_0 visible; ZXL dead -> PL region live

    for (int t = 0; t < T_; ++t) {
        const unsigned short* Hh = (t & 1) ? HF1h : HF0h;
        const unsigned short* Hl = (t & 1) ? HF1l : HF0l;
        unsigned short* Nh = (t & 1) ? HF0h : HF1h;
        unsigned short* Nl = (t & 1) ? HF0l : HF1l;
        float* PLw = (t & 1) ? PL1 : PL0;
        const float* PLr = (t & 1) ? PL0 : PL1;

        // A-frags of H_t (shared by gates and proj)
        short8 ah0 = *reinterpret_cast<const short8*>(Hh + c*HFS +      g*8);
        short8 al0 = *reinterpret_cast<const short8*>(Hl + c*HFS +      g*8);
        short8 ah1 = *reinterpret_cast<const short8*>(Hh + c*HFS + 32 + g*8);
        short8 al1 = *reinterpret_cast<const short8*>(Hl + c*HFS + 32 + g*8);

        // gates for LSTM step t+1 (input index t)
        const float* dptr = (t == 0) ? PRS : (FUT + (t-1)*16);
        f32x4 ai, af, ag, ao;
        #pragma unroll
        for (int r = 0; r < 4; ++r) {
            float2 dv = *reinterpret_cast<const float2*>(dptr + (4*g + r)*2);
            ai[r] = gci[r] + dv.x*wdi0 + dv.y*wdi1;
            af[r] = gcf[r] + dv.x*wdf0 + dv.y*wdf1;
            ag[r] = gcg[r] + dv.x*wdg0 + dv.y*wdg1;
            ao[r] = gco[r] + dv.x*wdo0 + dv.y*wdo1;
        }
        ai = MFMA(ah0,WIh0,ai); ai = MFMA(ah0,WIl0,ai); ai = MFMA(al0,WIh0,ai);
        ai = MFMA(ah1,WIh1,ai); ai = MFMA(ah1,WIl1,ai); ai = MFMA(al1,WIh1,ai);
        af = MFMA(ah0,WFh0,af); af = MFMA(ah0,WFl0,af); af = MFMA(al0,WFh0,af);
        af = MFMA(ah1,WFh1,af); af = MFMA(ah1,WFl1,af); af = MFMA(al1,WFh1,af);
        ag = MFMA(ah0,WGh0,ag); ag = MFMA(ah0,WGl0,ag); ag = MFMA(al0,WGh0,ag);
        ag = MFMA(ah1,WGh1,ag); ag = MFMA(ah1,WGl1,ag); ag = MFMA(al1,WGh1,ag);
        ao = MFMA(ah0,WOh0,ao); ao = MFMA(ah0,WOl0,ao); ao = MFMA(al0,WOh0,ao);
        ao = MFMA(ah1,WOh1,ao); ao = MFMA(ah1,WOl1,ao); ao = MFMA(al1,WOh1,ao);

        // proj(H_t) for t>=1 (reuses A-frags)
        if (t >= 1) do_proj(ah0, al0, ah1, al1, PLw);

        // cell update in registers -> H_{t+1}
        #pragma unroll
        for (int r = 0; r < 4; ++r) {
            float cc = sigf(af[r])*cst[r] + sigf(ai[r])*tanh_(ag[r]);
            cst[r] = cc;
            float hv = sigf(ao[r])*tanh_(cc);
            unsigned short hh, ll; splitf(hv, hh, ll);
            if (g < 2) {
                Nh[(4*g + r)*HFS + U] = hh;
                Nl[(4*g + r)*HFS + U] = ll;
            }
        }

        // GMM for H_{t-1} (proj written at iter t-1)
        if (t >= 2 && j < 128) do_gmm(PLr, FUT + (t-2)*16);

        __syncthreads();
    }

    // post-loop: proj(H_50) from HF0 (50 even), GMM(H_49) from PL1, then GMM(H_50)
    {
        short8 ah0 = *reinterpret_cast<const short8*>(HF0h + c*HFS +      g*8);
        short8 al0 = *reinterpret_cast<const short8*>(HF0l + c*HFS +      g*8);
        short8 ah1 = *reinterpret_cast<const short8*>(HF0h + c*HFS + 32 + g*8);
        short8 al1 = *reinterpret_cast<const short8*>(HF0l + c*HFS + 32 + g*8);
        do_proj(ah0, al0, ah1, al1, PL0);
        if (j < 128) do_gmm(PL1, FUT + 48*16);
        __syncthreads();
        if (j < 128) do_gmm(PL0, FUT + 49*16);
    }

    if (j < 128 && g3 == 0) out[blk*SPB + s3] = sum;
}

extern "C" void kernel_launch(void* const* d_in, const int* in_sizes, int n_in,
                              void* d_out, int out_size, void* d_ws, size_t ws_size,
                              hipStream_t stream) {
    const float* x     = (const float*)d_in[0];
    const float* z     = (const float*)d_in[1];
    const float* iseq  = (const float*)d_in[2];
    const float* pseq  = (const float*)d_in[3];
    const float* Wh0   = (const float*)d_in[4];
    const float* bh0   = (const float*)d_in[5];
    const float* Wc0   = (const float*)d_in[6];
    const float* bc0   = (const float*)d_in[7];
    const float* Wih   = (const float*)d_in[8];
    const float* Whh   = (const float*)d_in[9];
    const float* bih   = (const float*)d_in[10];
    const float* bhh   = (const float*)d_in[11];
    const float* Wpi   = (const float*)d_in[12];
    const float* bpi   = (const float*)d_in[13];
    const float* Wmu   = (const float*)d_in[14];
    const float* bmu   = (const float*)d_in[15];
    const float* Wls   = (const float*)d_in[16];
    const float* bls   = (const float*)d_in[17];
    const float* Wcorr = (const float*)d_in[18];
    const float* bcorr = (const float*)d_in[19];
    float* out = (float*)d_out;

    decoder_kernel<<<512, 256, 0, stream>>>(x, z, iseq, pseq, Wh0, bh0, Wc0, bc0,
                                            Wih, Whh, bih, bhh, Wpi, bpi, Wmu, bmu,
                                            Wls, bls, Wcorr, bcorr, out);
}

// Round 4
// 95.870 us; speedup vs baseline: 1.6519x; 1.6519x over previous
//
#include <hip/hip_runtime.h>

// Decoder: N=4096 LSTM sequences (K=16 x B=256), H=64, T=50, GMM head (GC=16, PD=2).
// Round 4: 256 blocks x 512 threads x 16 samples. Wave specialization:
//   waves 0-3 (LSTM): wave w owns all 4 gate tiles for units [16w,16w+16)
//     -> 24 MFMA/step + register cell update (c lane-resident, no gate LDS).
//   waves 4-7 (head): proj(H_t) 6 tiles (2/2/1/1) + GMM(t-1), fully overlapped.
// ONE barrier per step; H and PL double-buffered; full 16-row MFMA tiles.

#define T_ 50
#define SPB 16
#define ZXS 324
#define HFS 72
#define PLS 100

typedef __attribute__((ext_vector_type(8))) short short8;
typedef __attribute__((ext_vector_type(4))) float f32x4;

#define MFMA(a, b, c) __builtin_amdgcn_mfma_f32_16x16x32_bf16(a, b, c, 0, 0, 0)

__device__ __forceinline__ float sigf(float x)  { return 1.0f / (1.0f + __expf(-x)); }
__device__ __forceinline__ float tanh_(float x) { return 1.0f - 2.0f / (__expf(2.0f * x) + 1.0f); }

__device__ __forceinline__ void splitf(float f, unsigned short& hi, unsigned short& lo) {
    unsigned b = __float_as_uint(f);
    hi = (unsigned short)(b >> 16);
    float fh = __uint_as_float(b & 0xffff0000u);
    lo = (unsigned short)(__float_as_uint(f - fh) >> 16);
}

__device__ __forceinline__ void pack8(const float* p, short8& hi, short8& lo) {
    #pragma unroll
    for (int e = 0; e < 8; ++e) {
        unsigned short h, l;
        splitf(p[e], h, l);
        hi[e] = (short)h; lo[e] = (short)l;
    }
}

__launch_bounds__(512, 1)
__global__ void decoder_kernel(
    const float* __restrict__ x,       const float* __restrict__ z,
    const float* __restrict__ inp_seqs,const float* __restrict__ pred_seqs,
    const float* __restrict__ Wh0,     const float* __restrict__ bh0,
    const float* __restrict__ Wc0,     const float* __restrict__ bc0,
    const float* __restrict__ Wih,     const float* __restrict__ Whh,
    const float* __restrict__ bih,     const float* __restrict__ bhh,
    const float* __restrict__ Wpi,     const float* __restrict__ bpi,
    const float* __restrict__ Wmu,     const float* __restrict__ bmu,
    const float* __restrict__ Wls,     const float* __restrict__ bls,
    const float* __restrict__ Wcorr,   const float* __restrict__ bcorr,
    float* __restrict__ out)
{
    // floats: [0,5184) ZXL 16x324 (prologue) / PL0 [0,1600) PL1 [1600,3200)
    //         [5184,7488) HF: 4 ushort arrays of 16x72 (h0 hi, h0 lo, h1 hi, h1 lo)
    //         [7616,9216) FUT 50x32   [9216,9248) PRS
    __shared__ __align__(16) float smem[9248];
    float* ZXL = smem;
    float* PL0 = smem;
    float* PL1 = smem + 1600;
    unsigned short* HF0h = (unsigned short*)(smem + 5184);
    unsigned short* HF0l = HF0h + 1152;
    unsigned short* HF1h = HF0h + 2304;
    unsigned short* HF1l = HF0h + 3456;
    float* FUT = smem + 7616;
    float* PRS = smem + 9216;

    const int j = threadIdx.x;
    const int w = j >> 6;       // wave 0..7
    const int l = j & 63;
    const int g = l >> 4;       // k-group / D-row-group
    const int c = l & 15;       // A-row (sample) / B-col
    const int U = 16*(w & 3) + c;
    const int blk = blockIdx.x;

    // ---- fill ZXL (16 x 320, all rows real), FUT, PRS
    for (int e = j; e < SPB*320; e += 512) {
        int s = e / 320, k = e - s*320;
        int n = blk*SPB + s, kk = n >> 8, b = n & 255;
        ZXL[s*ZXS + k] = (k < 64) ? z[(kk*256 + b)*64 + k] : x[b*256 + (k - 64)];
    }
    for (int e = j; e < T_*SPB; e += 512) {
        int t = e >> 4, s = e & 15;
        int b = (blk*SPB + s) & 255;
        float2 v = *reinterpret_cast<const float2*>(pred_seqs + b*1200 + t*24 + 20);
        FUT[t*32 + s*2] = v.x; FUT[t*32 + s*2 + 1] = v.y;
    }
    if (j < SPB) {
        int b = (blk*SPB + j) & 255;
        float2 v = *reinterpret_cast<const float2*>(inp_seqs + b*192 + 188);
        PRS[j*2] = v.x; PRS[j*2 + 1] = v.y;
    }
    __syncthreads();

    // ---- per-role state
    float cst[4];
    f32x4 gci, gcf, gcg, gco;
    float wdi0=0,wdi1=0,wdf0=0,wdf1=0,wdg0=0,wdg1=0,wdo0=0,wdo1=0;
    short8 WIh0,WIl0,WIh1,WIl1, WFh0,WFl0,WFh1,WFl1,
           WGh0,WGl0,WGh1,WGl1, WOh0,WOl0,WOh1,WOl1;
    short8 qAh0,qAl0,qAh1,qAl1, qBh0,qBl0,qBh1,qBl1;
    float biasA = 0.0f, biasB = 0.0f;
    int ptA = 0, nproj = 0;

    auto projrow = [&](int r3, const float*& p, float& b) {
        if      (r3 < 16) { p = Wpi   + r3*64;      b = bpi[r3]; }
        else if (r3 < 48) { p = Wmu   + (r3-16)*64; b = bmu[r3-16]; }
        else if (r3 < 80) { p = Wls   + (r3-48)*64; b = bls[r3-48]; }
        else              { p = Wcorr + (r3-80)*64; b = bcorr[r3-80]; }
    };

    if (w < 4) {
        // ---- LSTM wave prologue: gates_const (4 tiles), c0 (1 tile)
        const int R0 = U, R1 = 64 + U, R2 = 128 + U, R3 = 192 + U;
        {
            float bi_ = bih[R0] + bhh[R0], bf_ = bih[R1] + bhh[R1];
            float bg_ = bih[R2] + bhh[R2], bo_ = bih[R3] + bhh[R3];
            gci = (f32x4){bi_,bi_,bi_,bi_}; gcf = (f32x4){bf_,bf_,bf_,bf_};
            gcg = (f32x4){bg_,bg_,bg_,bg_}; gco = (f32x4){bo_,bo_,bo_,bo_};
        }
        float bc_ = bc0[U];
        f32x4 c0a = (f32x4){bc_, bc_, bc_, bc_};
        for (int ks = 0; ks < 10; ++ks) {
            int k0 = ks*32 + g*8;
            short8 ah, al, b0h,b0l, b1h,b1l, b2h,b2l, b3h,b3l, bch,bcl;
            pack8(&ZXL[c*ZXS + k0], ah, al);
            pack8(Wih + R0*322 + k0, b0h, b0l);
            pack8(Wih + R1*322 + k0, b1h, b1l);
            pack8(Wih + R2*322 + k0, b2h, b2l);
            pack8(Wih + R3*322 + k0, b3h, b3l);
            pack8(Wc0 + U*320 + k0, bch, bcl);
            gci = MFMA(ah,b0h,gci); gci = MFMA(ah,b0l,gci); gci = MFMA(al,b0h,gci);
            gcf = MFMA(ah,b1h,gcf); gcf = MFMA(ah,b1l,gcf); gcf = MFMA(al,b1h,gcf);
            gcg = MFMA(ah,b2h,gcg); gcg = MFMA(ah,b2l,gcg); gcg = MFMA(al,b2h,gcg);
            gco = MFMA(ah,b3h,gco); gco = MFMA(ah,b3l,gco); gco = MFMA(al,b3h,gco);
            c0a = MFMA(ah,bch,c0a); c0a = MFMA(ah,bcl,c0a); c0a = MFMA(al,bch,c0a);
        }
        #pragma unroll
        for (int r = 0; r < 4; ++r) cst[r] = c0a[r];
        wdi0 = Wih[R0*322+320]; wdi1 = Wih[R0*322+321];
        wdf0 = Wih[R1*322+320]; wdf1 = Wih[R1*322+321];
        wdg0 = Wih[R2*322+320]; wdg1 = Wih[R2*322+321];
        wdo0 = Wih[R3*322+320]; wdo1 = Wih[R3*322+321];
        pack8(Whh + R0*64 +      g*8, WIh0, WIl0); pack8(Whh + R0*64 + 32 + g*8, WIh1, WIl1);
        pack8(Whh + R1*64 +      g*8, WFh0, WFl0); pack8(Whh + R1*64 + 32 + g*8, WFh1, WFl1);
        pack8(Whh + R2*64 +      g*8, WGh0, WGl0); pack8(Whh + R2*64 + 32 + g*8, WGh1, WGl1);
        pack8(Whh + R3*64 +      g*8, WOh0, WOl0); pack8(Whh + R3*64 + 32 + g*8, WOh1, WOl1);
    } else {
        // ---- head wave prologue: h0 tile (units 16v..16v+15), proj frags
        float bh_ = bh0[U];
        f32x4 h0a = (f32x4){bh_, bh_, bh_, bh_};
        for (int ks = 0; ks < 10; ++ks) {
            int k0 = ks*32 + g*8;
            short8 ah, al, bhh_, bhl_;
            pack8(&ZXL[c*ZXS + k0], ah, al);
            pack8(Wh0 + U*320 + k0, bhh_, bhl_);
            h0a = MFMA(ah,bhh_,h0a); h0a = MFMA(ah,bhl_,h0a); h0a = MFMA(al,bhh_,h0a);
        }
        #pragma unroll
        for (int r = 0; r < 4; ++r) {
            unsigned short hh, ll; splitf(h0a[r], hh, ll);
            HF0h[(4*g + r)*HFS + U] = hh;
            HF0l[(4*g + r)*HFS + U] = ll;
        }
        const int v = w - 4;
        nproj = (v < 2) ? 2 : 1;
        ptA = (v < 2) ? 2*v : (4 + (v - 2));     // 4:{0,1} 5:{2,3} 6:{4} 7:{5}
        {
            const float* p; projrow(ptA*16 + c, p, biasA);
            pack8(p +      g*8, qAh0, qAl0);
            pack8(p + 32 + g*8, qAh1, qAl1);
        }
        if (nproj == 2) {
            const float* p; projrow((ptA+1)*16 + c, p, biasB);
            pack8(p +      g*8, qBh0, qBl0);
            pack8(p + 32 + g*8, qBh1, qBl1);
        }
    }

    const int jj = j & 255;
    const int s3 = jj >> 4, g3 = jj & 15;
    float sum = 0.0f;

    auto do_proj = [&](const unsigned short* Hh, const unsigned short* Hl, float* PLw) {
        short8 ah0 = *reinterpret_cast<const short8*>(Hh + c*HFS +      g*8);
        short8 al0 = *reinterpret_cast<const short8*>(Hl + c*HFS +      g*8);
        short8 ah1 = *reinterpret_cast<const short8*>(Hh + c*HFS + 32 + g*8);
        short8 al1 = *reinterpret_cast<const short8*>(Hl + c*HFS + 32 + g*8);
        f32x4 pA = (f32x4){biasA, biasA, biasA, biasA};
        pA = MFMA(ah0,qAh0,pA); pA = MFMA(ah0,qAl0,pA); pA = MFMA(al0,qAh0,pA);
        pA = MFMA(ah1,qAh1,pA); pA = MFMA(ah1,qAl1,pA); pA = MFMA(al1,qAh1,pA);
        #pragma unroll
        for (int r = 0; r < 4; ++r) PLw[(4*g + r)*PLS + ptA*16 + c] = pA[r];
        if (nproj == 2) {
            f32x4 pB = (f32x4){biasB, biasB, biasB, biasB};
            pB = MFMA(ah0,qBh0,pB); pB = MFMA(ah0,qBl0,pB); pB = MFMA(al0,qBh0,pB);
            pB = MFMA(ah1,qBh1,pB); pB = MFMA(ah1,qBl1,pB); pB = MFMA(al1,qBh1,pB);
            #pragma unroll
            for (int r = 0; r < 4; ++r) PLw[(4*g + r)*PLS + (ptA+1)*16 + c] = pB[r];
        }
    };
    auto do_gmm = [&](const float* pl, const float* fut2) {
        const float* pls = pl + s3*PLS;
        float a_pi = pls[g3];
        float a_m0 = pls[16 + 2*g3], a_m1 = pls[17 + 2*g3];
        float l0   = pls[48 + 2*g3], l1   = pls[49 + 2*g3];
        float a_co = pls[80 + g3];
        float v0 = fut2[s3*2], v1 = fut2[s3*2 + 1];
        l0 = fminf(fmaxf(l0, -10.0f), 10.0f);
        l1 = fminf(fmaxf(l1, -10.0f), 10.0f);
        float z0 = (v0 - a_m0) * __expf(-l0);
        float z1 = (v1 - a_m1) * __expf(-l1);
        float ct = tanh_(a_co);
        float omr = 1.0f - ct*ct;
        float quad = z0*z0 + z1*z1 - 2.0f*ct*z0*z1;
        float comp = -1.8378770664093453f - (l0 + l1) - 0.5f*__logf(omr) - 0.5f*quad/omr;
        float a = a_pi + comp;
        float m1v = a, m2v = a_pi;
        #pragma unroll
        for (int off = 1; off < 16; off <<= 1) {
            m1v = fmaxf(m1v, __shfl_xor(m1v, off));
            m2v = fmaxf(m2v, __shfl_xor(m2v, off));
        }
        float e1 = __expf(a - m1v), e2 = __expf(a_pi - m2v);
        #pragma unroll
        for (int off = 1; off < 16; off <<= 1) {
            e1 += __shfl_xor(e1, off);
            e2 += __shfl_xor(e2, off);
        }
        float logp = (m1v + __logf(e1)) - (m2v + __logf(e2));
        sum += fminf(logp, 50.0f);
    };

    __syncthreads();   // H_0 visible; ZXL dead -> PL region live

    for (int t = 0; t < T_; ++t) {
        const unsigned short* Hh = (t & 1) ? HF1h : HF0h;
        const unsigned short* Hl = (t & 1) ? HF1l : HF0l;
        if (w < 4) {
            unsigned short* Nh = (t & 1) ? HF0h : HF1h;
            unsigned short* Nl = (t & 1) ? HF0l : HF1l;
            short8 ah0 = *reinterpret_cast<const short8*>(Hh + c*HFS +      g*8);
            short8 al0 = *reinterpret_cast<const short8*>(Hl + c*HFS +      g*8);
            short8 ah1 = *reinterpret_cast<const short8*>(Hh + c*HFS + 32 + g*8);
            short8 al1 = *reinterpret_cast<const short8*>(Hl + c*HFS + 32 + g*8);
            const float* dptr = (t == 0) ? PRS : (FUT + (t-1)*32);
            f32x4 ai, af, ag, ao;
            #pragma unroll
            for (int r = 0; r < 4; ++r) {
                float2 dv = *reinterpret_cast<const float2*>(dptr + (4*g + r)*2);
                ai[r] = gci[r] + dv.x*wdi0 + dv.y*wdi1;
                af[r] = gcf[r] + dv.x*wdf0 + dv.y*wdf1;
                ag[r] = gcg[r] + dv.x*wdg0 + dv.y*wdg1;
                ao[r] = gco[r] + dv.x*wdo0 + dv.y*wdo1;
            }
            ai = MFMA(ah0,WIh0,ai); ai = MFMA(ah0,WIl0,ai); ai = MFMA(al0,WIh0,ai);
            ai = MFMA(ah1,WIh1,ai); ai = MFMA(ah1,WIl1,ai); ai = MFMA(al1,WIh1,ai);
            af = MFMA(ah0,WFh0,af); af = MFMA(ah0,WFl0,af); af = MFMA(al0,WFh0,af);
            af = MFMA(ah1,WFh1,af); af = MFMA(ah1,WFl1,af); af = MFMA(al1,WFh1,af);
            ag = MFMA(ah0,WGh0,ag); ag = MFMA(ah0,WGl0,ag); ag = MFMA(al0,WGh0,ag);
            ag = MFMA(ah1,WGh1,ag); ag = MFMA(ah1,WGl1,ag); ag = MFMA(al1,WGh1,ag);
            ao = MFMA(ah0,WOh0,ao); ao = MFMA(ah0,WOl0,ao); ao = MFMA(al0,WOh0,ao);
            ao = MFMA(ah1,WOh1,ao); ao = MFMA(ah1,WOl1,ao); ao = MFMA(al1,WOh1,ao);
            #pragma unroll
            for (int r = 0; r < 4; ++r) {
                float cc = sigf(af[r])*cst[r] + sigf(ai[r])*tanh_(ag[r]);
                cst[r] = cc;
                float hv = sigf(ao[r])*tanh_(cc);
                unsigned short hh, ll; splitf(hv, hh, ll);
                Nh[(4*g + r)*HFS + U] = hh;
                Nl[(4*g + r)*HFS + U] = ll;
            }
        } else {
            if (t >= 1) do_proj(Hh, Hl, (t & 1) ? PL1 : PL0);
            if (t >= 2) do_gmm((t & 1) ? PL0 : PL1, FUT + (t-2)*32);
        }
        __syncthreads();
    }

    // epilogue: proj(H_50) (parity: HF0) -> PL0; GMM(H_49)=PL1; sync; GMM(H_50)=PL0
    if (w >= 4) {
        do_proj(HF0h, HF0l, PL0);
        do_gmm(PL1, FUT + 48*32);
    }
    __syncthreads();
    if (w >= 4) {
        do_gmm(PL0, FUT + 49*32);
        if (g3 == 0) out[blk*SPB + s3] = sum;
    }
}

extern "C" void kernel_launch(void* const* d_in, const int* in_sizes, int n_in,
                              void* d_out, int out_size, void* d_ws, size_t ws_size,
                              hipStream_t stream) {
    const float* x     = (const float*)d_in[0];
    const float* z     = (const float*)d_in[1];
    const float* iseq  = (const float*)d_in[2];
    const float* pseq  = (const float*)d_in[3];
    const float* Wh0   = (const float*)d_in[4];
    const float* bh0   = (const float*)d_in[5];
    const float* Wc0   = (const float*)d_in[6];
    const float* bc0   = (const float*)d_in[7];
    const float* Wih   = (const float*)d_in[8];
    const float* Whh   = (const float*)d_in[9];
    const float* bih   = (const float*)d_in[10];
    const float* bhh   = (const float*)d_in[11];
    const float* Wpi   = (const float*)d_in[12];
    const float* bpi   = (const float*)d_in[13];
    const float* Wmu   = (const float*)d_in[14];
    const float* bmu   = (const float*)d_in[15];
    const float* Wls   = (const float*)d_in[16];
    const float* bls   = (const float*)d_in[17];
    const float* Wcorr = (const float*)d_in[18];
    const float* bcorr = (const float*)d_in[19];
    float* out = (float*)d_out;

    decoder_kernel<<<256, 512, 0, stream>>>(x, z, iseq, pseq, Wh0, bh0, Wc0, bc0,
                                            Wih, Whh, bih, bhh, Wpi, bpi, Wmu, bmu,
                                            Wls, bls, Wcorr, bcorr, out);
}